// Round 1
// baseline (2993.535 us; speedup 1.0000x reference)
//
#include <hip/hip_runtime.h>
#include <cstdint>

// Problem constants
#define BB 64
#define TT 1024
#define DD 256
#define HH 128
#define G4 512   // 4*H
#define NTAG 3

typedef __attribute__((ext_vector_type(8))) short bf16x8;
typedef __attribute__((ext_vector_type(4))) float f32x4;

__device__ __forceinline__ unsigned short f2bf(float f) {
    uint32_t u = __builtin_bit_cast(uint32_t, f);
    uint32_t r = (u + 0x7FFFu + ((u >> 16) & 1u)) >> 16;
    return (unsigned short)r;
}
__device__ __forceinline__ float bf2f(unsigned short s) {
    uint32_t u = ((uint32_t)s) << 16;
    return __builtin_bit_cast(float, u);
}
__device__ __forceinline__ float sigm(float x) {
    return 1.f / (1.f + exp2f(x * -1.44269504f));
}
__device__ __forceinline__ float tanh_f(float x) {
    return 1.f - 2.f / (exp2f(x * 2.88539008f) + 1.f);
}

// ---------------- fp32 -> bf16 conversion (vectorized x4) ----------------
__global__ void cvt4_kernel(const float* __restrict__ in, unsigned short* __restrict__ out, int n4) {
    int idx = blockIdx.x * blockDim.x + threadIdx.x;
    if (idx < n4) {
        float4 v = ((const float4*)in)[idx];
        ushort4 o;
        o.x = f2bf(v.x); o.y = f2bf(v.y); o.z = f2bf(v.z); o.w = f2bf(v.w);
        ((ushort4*)out)[idx] = o;
    }
}

// ---------------- input-projection GEMM: G = A @ W^T + b_ih + b_hh ----------------
// A: [65536, 256] bf16 row-major. W: [512, 256] bf16 row-major (N,K). G: [65536,512] bf16.
// grid (1024, 4, 2): x = 64-row M block, y = 128-col N strip, z = direction.
__global__ __launch_bounds__(256) void gemm_ih(
    const unsigned short* __restrict__ A,
    const unsigned short* __restrict__ W0, const unsigned short* __restrict__ W1,
    const float* __restrict__ bih0, const float* __restrict__ bhh0,
    const float* __restrict__ bih1, const float* __restrict__ bhh1,
    unsigned short* __restrict__ G0, unsigned short* __restrict__ G1)
{
    const int dir = blockIdx.z;
    const unsigned short* W = dir ? W1 : W0;
    const float* bih = dir ? bih1 : bih0;
    const float* bhh = dir ? bhh1 : bhh0;
    unsigned short* G = dir ? G1 : G0;

    const int wave = threadIdx.x >> 6;
    const int lane = threadIdx.x & 63;
    const int m16 = lane & 15;
    const int quad = lane >> 4;

    const int rowA = blockIdx.x * 64 + wave * 16 + m16;
    const int n0 = blockIdx.y * 128;

    // preload 8 A fragments (K = 8 x 32)
    bf16x8 afrag[8];
    const uint4* Abase = (const uint4*)(A + (size_t)rowA * DD + quad * 8);
#pragma unroll
    for (int kk = 0; kk < 8; kk++) {
        uint4 u = Abase[kk * 2]; // kk*32 ushorts = kk*2 uint4
        afrag[kk] = __builtin_bit_cast(bf16x8, u);
    }

#pragma unroll
    for (int nt = 0; nt < 8; nt++) {
        const int n = n0 + nt * 16 + m16;
        f32x4 acc = {0.f, 0.f, 0.f, 0.f};
        const uint4* Wbase = (const uint4*)(W + (size_t)n * DD + quad * 8);
#pragma unroll
        for (int kk = 0; kk < 8; kk++) {
            uint4 u = Wbase[kk * 2];
            bf16x8 bfrag = __builtin_bit_cast(bf16x8, u);
            acc = __builtin_amdgcn_mfma_f32_16x16x32_bf16(afrag[kk], bfrag, acc, 0, 0, 0);
        }
        const float bias = bih[n] + bhh[n];
        const int outRowBase = blockIdx.x * 64 + wave * 16 + quad * 4;
#pragma unroll
        for (int r = 0; r < 4; r++) {
            G[(size_t)(outRowBase + r) * G4 + n] = f2bf(acc[r] + bias);
        }
    }
}

// ---------------- LSTM recurrent scan ----------------
// grid (64, 2): x = batch, y = direction (0 fwd, 1 rev). 512 threads; thread j = gate row j.
// Each thread keeps w_hh[j][0:128] in VGPRs. h broadcast via LDS.
__global__ __launch_bounds__(512, 2) void lstm_scan(
    const unsigned short* __restrict__ Gf, const unsigned short* __restrict__ Gr,
    const float* __restrict__ whh_f, const float* __restrict__ whh_r,
    unsigned short* __restrict__ out)
{
    const int b = blockIdx.x;
    const int dir = blockIdx.y;
    const unsigned short* G = dir ? Gr : Gf;
    const float* whh = dir ? whh_r : whh_f;
    const int j = threadIdx.x;

    // preload this gate's recurrent weights into registers
    float w[HH];
    {
        const float4* wr = (const float4*)(whh + (size_t)j * HH);
#pragma unroll
        for (int q = 0; q < HH / 4; q++) {
            float4 v = wr[q];
            w[4 * q + 0] = v.x; w[4 * q + 1] = v.y; w[4 * q + 2] = v.z; w[4 * q + 3] = v.w;
        }
    }

    __shared__ __align__(16) float h_s[HH];
    __shared__ float g_s[G4];

    if (j < HH) h_s[j] = 0.f;
    float c = 0.f;
    __syncthreads();

    for (int s = 0; s < TT; s++) {
        const int t = dir ? (TT - 1 - s) : s;
        // issue gate-preact load early; consumed after the FMA loop
        const float gin = bf2f(G[((size_t)b * TT + t) * G4 + j]);

        float acc = 0.f;
        const float4* h4 = (const float4*)h_s;
#pragma unroll
        for (int q = 0; q < HH / 4; q++) {
            float4 hv = h4[q];
            acc = fmaf(w[4 * q + 0], hv.x, acc);
            acc = fmaf(w[4 * q + 1], hv.y, acc);
            acc = fmaf(w[4 * q + 2], hv.z, acc);
            acc = fmaf(w[4 * q + 3], hv.w, acc);
        }
        acc += gin;
        g_s[j] = acc;
        __syncthreads();

        if (j < HH) {
            const float ig = sigm(g_s[j]);
            const float fg = sigm(g_s[HH + j]);
            const float gg = tanh_f(g_s[2 * HH + j]);
            const float og = sigm(g_s[3 * HH + j]);
            c = fg * c + ig * gg;
            const float h = og * tanh_f(c);
            h_s[j] = h;
            out[((size_t)b * TT + t) * (2 * HH) + dir * HH + j] = f2bf(h);
        }
        __syncthreads();
    }
}

// ---------------- emissions: out1 [65536,256] bf16 @ fc_w^T [3,256] + fc_b ----------------
__global__ __launch_bounds__(256) void emis_kernel(
    const unsigned short* __restrict__ out1,
    const float* __restrict__ fcw, const float* __restrict__ fcb,
    float* __restrict__ dout)
{
    __shared__ float wsm[NTAG * 256];
    for (int i = threadIdx.x; i < NTAG * 256; i += 256) wsm[i] = fcw[i];
    __syncthreads();

    const int bt = blockIdx.x * 256 + threadIdx.x;
    float a0 = fcb[0], a1 = fcb[1], a2 = fcb[2];
    const uint4* row = (const uint4*)(out1 + (size_t)bt * 256);
#pragma unroll 4
    for (int k8 = 0; k8 < 32; k8++) {
        uint4 u = row[k8];
        const int kb = k8 * 8;
        uint32_t p[4] = {u.x, u.y, u.z, u.w};
#pragma unroll
        for (int e = 0; e < 4; e++) {
            float flo = __builtin_bit_cast(float, p[e] << 16);
            float fhi = __builtin_bit_cast(float, p[e] & 0xFFFF0000u);
            const int k = kb + 2 * e;
            a0 = fmaf(flo, wsm[0 * 256 + k], a0);
            a1 = fmaf(flo, wsm[1 * 256 + k], a1);
            a2 = fmaf(flo, wsm[2 * 256 + k], a2);
            a0 = fmaf(fhi, wsm[0 * 256 + k + 1], a0);
            a1 = fmaf(fhi, wsm[1 * 256 + k + 1], a1);
            a2 = fmaf(fhi, wsm[2 * 256 + k + 1], a2);
        }
    }
    dout[1 + (size_t)bt * 3 + 0] = a0;
    dout[1 + (size_t)bt * 3 + 1] = a1;
    dout[1 + (size_t)bt * 3 + 2] = a2;
}

// ---------------- CRF NLL ----------------
__device__ __forceinline__ float sel3(int i, float a, float b, float c) {
    return i == 0 ? a : (i == 1 ? b : c);
}
__device__ __forceinline__ float lse3(float a, float b, float c) {
    float m = fmaxf(a, fmaxf(b, c));
    float s = exp2f((a - m) * 1.44269504f) + exp2f((b - m) * 1.44269504f) + exp2f((c - m) * 1.44269504f);
    return m + log2f(s) * 0.69314718f;
}

__global__ void crf_kernel(const int* __restrict__ tags,
                           const float* __restrict__ start, const float* __restrict__ end,
                           const float* __restrict__ trans, float* __restrict__ dout)
{
    const int b = threadIdx.x; // 64 threads, one wave
    float tr[3][3];
#pragma unroll
    for (int i = 0; i < 3; i++)
#pragma unroll
        for (int jj = 0; jj < 3; jj++) tr[i][jj] = trans[i * 3 + jj];
    const float s0 = start[0], s1 = start[1], s2 = start[2];
    const float e0c = end[0], e1c = end[1], e2c = end[2];

    const float* em = dout + 1 + (size_t)b * TT * 3;
    const int* tg = tags + (size_t)b * TT;

    int tprev = tg[0];
    float a0 = s0 + em[0], a1 = s1 + em[1], a2 = s2 + em[2];
    float num = sel3(tprev, s0, s1, s2) + sel3(tprev, em[0], em[1], em[2]);

    for (int t = 1; t < TT; t++) {
        const float e0 = em[t * 3 + 0], e1 = em[t * 3 + 1], e2 = em[t * 3 + 2];
        const int tt = tg[t];
        const float ee = sel3(tt, e0, e1, e2);
        const float trv = sel3(tprev,
                               sel3(tt, tr[0][0], tr[0][1], tr[0][2]),
                               sel3(tt, tr[1][0], tr[1][1], tr[1][2]),
                               sel3(tt, tr[2][0], tr[2][1], tr[2][2]));
        num += ee + trv;
        tprev = tt;
        const float n0 = lse3(a0 + tr[0][0], a1 + tr[1][0], a2 + tr[2][0]) + e0;
        const float n1 = lse3(a0 + tr[0][1], a1 + tr[1][1], a2 + tr[2][1]) + e1;
        const float n2 = lse3(a0 + tr[0][2], a1 + tr[1][2], a2 + tr[2][2]) + e2;
        a0 = n0; a1 = n1; a2 = n2;
    }
    num += sel3(tprev, e0c, e1c, e2c);
    const float logZ = lse3(a0 + e0c, a1 + e1c, a2 + e2c);
    float val = logZ - num; // per-batch contribution to loss

#pragma unroll
    for (int off = 32; off > 0; off >>= 1) val += __shfl_down(val, off, 64);
    if (b == 0) dout[0] = val / (float)BB;
}

// ---------------- launch ----------------
extern "C" void kernel_launch(void* const* d_in, const int* in_sizes, int n_in,
                              void* d_out, int out_size, void* d_ws, size_t ws_size,
                              hipStream_t stream) {
    const float* x        = (const float*)d_in[0];
    const int*   tags     = (const int*)d_in[1];
    const float* w_ih_l0  = (const float*)d_in[2];
    const float* w_hh_l0  = (const float*)d_in[3];
    const float* b_ih_l0  = (const float*)d_in[4];
    const float* b_hh_l0  = (const float*)d_in[5];
    const float* w_ih_l0r = (const float*)d_in[6];
    const float* w_hh_l0r = (const float*)d_in[7];
    const float* b_ih_l0r = (const float*)d_in[8];
    const float* b_hh_l0r = (const float*)d_in[9];
    const float* w_ih_l1  = (const float*)d_in[10];
    const float* w_hh_l1  = (const float*)d_in[11];
    const float* b_ih_l1  = (const float*)d_in[12];
    const float* b_hh_l1  = (const float*)d_in[13];
    const float* w_ih_l1r = (const float*)d_in[14];
    const float* w_hh_l1r = (const float*)d_in[15];
    const float* b_ih_l1r = (const float*)d_in[16];
    const float* b_hh_l1r = (const float*)d_in[17];
    const float* fc_w     = (const float*)d_in[18];
    const float* fc_b     = (const float*)d_in[19];
    const float* crf_start= (const float*)d_in[20];
    const float* crf_end  = (const float*)d_in[21];
    const float* crf_trans= (const float*)d_in[22];
    float* dout = (float*)d_out;

    uint8_t* ws = (uint8_t*)d_ws;
    // workspace layout (bytes)
    unsigned short* xb   = (unsigned short*)(ws + 0);          // 33.5 MB, reused as out1 later
    unsigned short* out1 = xb;
    unsigned short* out0 = (unsigned short*)(ws + 33554432);   // 33.5 MB
    unsigned short* Gf   = (unsigned short*)(ws + 67108864);   // 67 MB
    unsigned short* Gr   = (unsigned short*)(ws + 134217728);  // 67 MB
    unsigned short* wb0  = (unsigned short*)(ws + 201326592);  // 4 x 256 KB
    unsigned short* wb0r = wb0 + 131072;
    unsigned short* wb1  = wb0 + 262144;
    unsigned short* wb1r = wb0 + 393216;

    // 1. convert x and the 4 w_ih matrices to bf16
    cvt4_kernel<<<dim3((16777216 / 4 + 255) / 256), dim3(256), 0, stream>>>(x, xb, 16777216 / 4);
    cvt4_kernel<<<dim3(128), dim3(256), 0, stream>>>(w_ih_l0,  wb0,  131072 / 4);
    cvt4_kernel<<<dim3(128), dim3(256), 0, stream>>>(w_ih_l0r, wb0r, 131072 / 4);
    cvt4_kernel<<<dim3(128), dim3(256), 0, stream>>>(w_ih_l1,  wb1,  131072 / 4);
    cvt4_kernel<<<dim3(128), dim3(256), 0, stream>>>(w_ih_l1r, wb1r, 131072 / 4);

    // 2. layer 0: input projection + scan
    gemm_ih<<<dim3(1024, 4, 2), dim3(256), 0, stream>>>(
        xb, wb0, wb0r, b_ih_l0, b_hh_l0, b_ih_l0r, b_hh_l0r, Gf, Gr);
    lstm_scan<<<dim3(64, 2), dim3(512), 0, stream>>>(Gf, Gr, w_hh_l0, w_hh_l0r, out0);

    // 3. layer 1: input projection (reusing G buffers) + scan
    gemm_ih<<<dim3(1024, 4, 2), dim3(256), 0, stream>>>(
        out0, wb1, wb1r, b_ih_l1, b_hh_l1, b_ih_l1r, b_hh_l1r, Gf, Gr);
    lstm_scan<<<dim3(64, 2), dim3(512), 0, stream>>>(Gf, Gr, w_hh_l1, w_hh_l1r, out1);

    // 4. emissions
    emis_kernel<<<dim3(256), dim3(256), 0, stream>>>(out1, fc_w, fc_b, dout);

    // 5. CRF NLL -> dout[0]
    crf_kernel<<<dim3(1), dim3(64), 0, stream>>>(tags, crf_start, crf_end, crf_trans, dout);
}

// Round 2
// 2635.610 us; speedup vs baseline: 1.1358x; 1.1358x over previous
//
#include <hip/hip_runtime.h>
#include <cstdint>

// Problem constants
#define BB 64
#define TT 1024
#define DD 256
#define HH 128
#define G4 512   // 4*H
#define NTAG 3

typedef __attribute__((ext_vector_type(8))) short bf16x8;
typedef __attribute__((ext_vector_type(4))) float f32x4;

__device__ __forceinline__ unsigned short f2bf(float f) {
    uint32_t u = __builtin_bit_cast(uint32_t, f);
    uint32_t r = (u + 0x7FFFu + ((u >> 16) & 1u)) >> 16;
    return (unsigned short)r;
}
__device__ __forceinline__ float bf2f(unsigned short s) {
    uint32_t u = ((uint32_t)s) << 16;
    return __builtin_bit_cast(float, u);
}
// raw HW transcendentals: v_exp_f32 / v_rcp_f32
__device__ __forceinline__ float sigm(float x) {
    return __builtin_amdgcn_rcpf(1.f + __builtin_amdgcn_exp2f(x * -1.44269504f));
}
__device__ __forceinline__ float tanh_f(float x) {
    // tanh(x) = 1 - 2/(1+e^{2x})
    return 1.f - 2.f * __builtin_amdgcn_rcpf(1.f + __builtin_amdgcn_exp2f(x * 2.88539008f));
}

// ---------------- fp32 -> bf16 conversion (vectorized x4) ----------------
__global__ void cvt4_kernel(const float* __restrict__ in, unsigned short* __restrict__ out, int n4) {
    int idx = blockIdx.x * blockDim.x + threadIdx.x;
    if (idx < n4) {
        float4 v = ((const float4*)in)[idx];
        ushort4 o;
        o.x = f2bf(v.x); o.y = f2bf(v.y); o.z = f2bf(v.z); o.w = f2bf(v.w);
        ((ushort4*)out)[idx] = o;
    }
}

// ---------------- input-projection GEMM: G = A @ W^T + b_ih + b_hh ----------------
// A: [65536, 256] bf16 row-major. W: [512, 256] bf16 row-major (N,K). G: [65536,512] bf16.
// grid (1024, 4, 2): x = 64-row M block, y = 128-col N strip, z = direction.
__global__ __launch_bounds__(256) void gemm_ih(
    const unsigned short* __restrict__ A,
    const unsigned short* __restrict__ W0, const unsigned short* __restrict__ W1,
    const float* __restrict__ bih0, const float* __restrict__ bhh0,
    const float* __restrict__ bih1, const float* __restrict__ bhh1,
    unsigned short* __restrict__ G0, unsigned short* __restrict__ G1)
{
    const int dir = blockIdx.z;
    const unsigned short* W = dir ? W1 : W0;
    const float* bih = dir ? bih1 : bih0;
    const float* bhh = dir ? bhh1 : bhh0;
    unsigned short* G = dir ? G1 : G0;

    const int wave = threadIdx.x >> 6;
    const int lane = threadIdx.x & 63;
    const int m16 = lane & 15;
    const int quad = lane >> 4;

    const int rowA = blockIdx.x * 64 + wave * 16 + m16;
    const int n0 = blockIdx.y * 128;

    // preload 8 A fragments (K = 8 x 32)
    bf16x8 afrag[8];
    const uint4* Abase = (const uint4*)(A + (size_t)rowA * DD + quad * 8);
#pragma unroll
    for (int kk = 0; kk < 8; kk++) {
        uint4 u = Abase[kk * 2]; // kk*32 ushorts = kk*2 uint4
        afrag[kk] = __builtin_bit_cast(bf16x8, u);
    }

#pragma unroll
    for (int nt = 0; nt < 8; nt++) {
        const int n = n0 + nt * 16 + m16;
        f32x4 acc = {0.f, 0.f, 0.f, 0.f};
        const uint4* Wbase = (const uint4*)(W + (size_t)n * DD + quad * 8);
#pragma unroll
        for (int kk = 0; kk < 8; kk++) {
            uint4 u = Wbase[kk * 2];
            bf16x8 bfrag = __builtin_bit_cast(bf16x8, u);
            acc = __builtin_amdgcn_mfma_f32_16x16x32_bf16(afrag[kk], bfrag, acc, 0, 0, 0);
        }
        const float bias = bih[n] + bhh[n];
        const int outRowBase = blockIdx.x * 64 + wave * 16 + quad * 4;
#pragma unroll
        for (int r = 0; r < 4; r++) {
            G[(size_t)(outRowBase + r) * G4 + n] = f2bf(acc[r] + bias);
        }
    }
}

// ---------------- MFMA LSTM recurrent scan ----------------
// grid (32, 2): x = batch pair (2 batches), y = direction. 512 threads = 8 waves.
// Per step: h[2x128] (padded to 16 rows in LDS, bf16) @ w_hh^T [128x512] via MFMA,
// gates repacked through LDS, dense nonlinearity on threads 0..255, double-buffered h.
// w_hh fragments live in VGPRs for the whole scan (converted fp32->bf16 at preload).
__global__ __launch_bounds__(512, 2) void lstm_scan_mfma(
    const unsigned short* __restrict__ Gf, const unsigned short* __restrict__ Gr,
    const float* __restrict__ whh_f, const float* __restrict__ whh_r,
    unsigned short* __restrict__ out)
{
    const int bp = blockIdx.x;          // batches 2*bp, 2*bp+1
    const int dir = blockIdx.y;
    const unsigned short* G = dir ? Gr : Gf;
    const float* W = dir ? whh_r : whh_f;

    const int tid = threadIdx.x;
    const int wv = tid >> 6;
    const int lane = tid & 63;
    const int n16 = lane & 15;
    const int quad = lane >> 4;

    // h: 2 buffers x 16 rows x (128+8) ushorts; +8 pad -> 2-way (free) LDS bank pattern
    __shared__ __align__(16) unsigned short h_lds[2][16][136];
    __shared__ __align__(8) float gates_lds[G4][2];

    for (int i = tid; i < 2 * 16 * 136; i += 512) ((unsigned short*)h_lds)[i] = 0;

    // preload b-fragments: wave wv owns N-tiles 4*wv+p (p=0..3); B[k][n] = w_hh[n][k]
    bf16x8 bfrag[4][4];
#pragma unroll
    for (int p = 0; p < 4; p++) {
        const int n = wv * 64 + p * 16 + n16;
        const float* Wr = W + (size_t)n * HH + quad * 8;
#pragma unroll
        for (int kc = 0; kc < 4; kc++) {
            float4 v0 = ((const float4*)(Wr + kc * 32))[0];
            float4 v1 = ((const float4*)(Wr + kc * 32))[1];
            bf16x8 f;
            f[0] = (short)f2bf(v0.x); f[1] = (short)f2bf(v0.y);
            f[2] = (short)f2bf(v0.z); f[3] = (short)f2bf(v0.w);
            f[4] = (short)f2bf(v1.x); f[5] = (short)f2bf(v1.y);
            f[6] = (short)f2bf(v1.z); f[7] = (short)f2bf(v1.w);
            bfrag[p][kc] = f;
        }
    }

    // dense-phase identity (threads 0..255): b in {0,1}, hcol in [0,128)
    const int bb = tid >> 7;
    const int hcol = tid & 127;
    const int bglob = bp * 2 + bb;
    float c = 0.f;

    __syncthreads();

    // prefetch G for step 0
    float gpre[4] = {0.f, 0.f, 0.f, 0.f};
    if (tid < 256) {
        const int t0 = dir ? (TT - 1) : 0;
        const unsigned short* gp = G + ((size_t)bglob * TT + t0) * G4 + hcol;
#pragma unroll
        for (int g = 0; g < 4; g++) gpre[g] = bf2f(gp[g * HH]);
    }

    for (int s = 0; s < TT; s++) {
        const int t = dir ? (TT - 1 - s) : s;
        const int buf = s & 1;

        // prefetch next step's gate preacts (hides HBM latency behind MFMA phase)
        float gnext[4] = {0.f, 0.f, 0.f, 0.f};
        if (tid < 256 && s + 1 < TT) {
            const int tn = dir ? (TT - 2 - s) : (s + 1);
            const unsigned short* gp = G + ((size_t)bglob * TT + tn) * G4 + hcol;
#pragma unroll
            for (int g = 0; g < 4; g++) gnext[g] = bf2f(gp[g * HH]);
        }

        // phase A: gates = h @ w_hh^T  (rows 2..15 of h are zero padding)
        bf16x8 afrag[4];
#pragma unroll
        for (int kc = 0; kc < 4; kc++) {
            const uint4* hp = (const uint4*)&h_lds[buf][n16][kc * 32 + quad * 8];
            afrag[kc] = __builtin_bit_cast(bf16x8, hp[0]);
        }
#pragma unroll
        for (int p = 0; p < 4; p++) {
            f32x4 acc = {0.f, 0.f, 0.f, 0.f};
#pragma unroll
            for (int kc = 0; kc < 4; kc++)
                acc = __builtin_amdgcn_mfma_f32_16x16x32_bf16(afrag[kc], bfrag[p][kc], acc, 0, 0, 0);
            if (quad == 0) { // C rows 0,1 = batches (row = quad*4 + reg)
                const int n = wv * 64 + p * 16 + n16;
                gates_lds[n][0] = acc[0];
                gates_lds[n][1] = acc[1];
            }
        }
        __syncthreads();

        // phase B: dense nonlinearity, 256 active threads (one (b,hcol) each)
        if (tid < 256) {
            const float gi = gates_lds[hcol          ][bb] + gpre[0];
            const float gf = gates_lds[hcol + HH     ][bb] + gpre[1];
            const float gg = gates_lds[hcol + 2 * HH ][bb] + gpre[2];
            const float go = gates_lds[hcol + 3 * HH ][bb] + gpre[3];
            const float ig = sigm(gi);
            const float fg = sigm(gf);
            const float gt = tanh_f(gg);
            const float og = sigm(go);
            c = fg * c + ig * gt;
            const float h = og * tanh_f(c);
            const unsigned short hb = f2bf(h);
            h_lds[buf ^ 1][bb][hcol] = hb;
            out[((size_t)bglob * TT + t) * (2 * HH) + dir * HH + hcol] = hb;
        }
#pragma unroll
        for (int g = 0; g < 4; g++) gpre[g] = gnext[g];
        __syncthreads();
    }
}

// ---------------- emissions: out1 [65536,256] bf16 @ fc_w^T [3,256] + fc_b ----------------
__global__ __launch_bounds__(256) void emis_kernel(
    const unsigned short* __restrict__ out1,
    const float* __restrict__ fcw, const float* __restrict__ fcb,
    float* __restrict__ dout)
{
    __shared__ float wsm[NTAG * 256];
    for (int i = threadIdx.x; i < NTAG * 256; i += 256) wsm[i] = fcw[i];
    __syncthreads();

    const int bt = blockIdx.x * 256 + threadIdx.x;
    float a0 = fcb[0], a1 = fcb[1], a2 = fcb[2];
    const uint4* row = (const uint4*)(out1 + (size_t)bt * 256);
#pragma unroll 4
    for (int k8 = 0; k8 < 32; k8++) {
        uint4 u = row[k8];
        const int kb = k8 * 8;
        uint32_t p[4] = {u.x, u.y, u.z, u.w};
#pragma unroll
        for (int e = 0; e < 4; e++) {
            float flo = __builtin_bit_cast(float, p[e] << 16);
            float fhi = __builtin_bit_cast(float, p[e] & 0xFFFF0000u);
            const int k = kb + 2 * e;
            a0 = fmaf(flo, wsm[0 * 256 + k], a0);
            a1 = fmaf(flo, wsm[1 * 256 + k], a1);
            a2 = fmaf(flo, wsm[2 * 256 + k], a2);
            a0 = fmaf(fhi, wsm[0 * 256 + k + 1], a0);
            a1 = fmaf(fhi, wsm[1 * 256 + k + 1], a1);
            a2 = fmaf(fhi, wsm[2 * 256 + k + 1], a2);
        }
    }
    dout[1 + (size_t)bt * 3 + 0] = a0;
    dout[1 + (size_t)bt * 3 + 1] = a1;
    dout[1 + (size_t)bt * 3 + 2] = a2;
}

// ---------------- CRF NLL ----------------
__device__ __forceinline__ float sel3(int i, float a, float b, float c) {
    return i == 0 ? a : (i == 1 ? b : c);
}
__device__ __forceinline__ float lse3(float a, float b, float c) {
    float m = fmaxf(a, fmaxf(b, c));
    float s = exp2f((a - m) * 1.44269504f) + exp2f((b - m) * 1.44269504f) + exp2f((c - m) * 1.44269504f);
    return m + log2f(s) * 0.69314718f;
}

__global__ void crf_kernel(const int* __restrict__ tags,
                           const float* __restrict__ start, const float* __restrict__ end,
                           const float* __restrict__ trans, float* __restrict__ dout)
{
    const int b = threadIdx.x; // 64 threads, one wave
    float tr[3][3];
#pragma unroll
    for (int i = 0; i < 3; i++)
#pragma unroll
        for (int jj = 0; jj < 3; jj++) tr[i][jj] = trans[i * 3 + jj];
    const float s0 = start[0], s1 = start[1], s2 = start[2];
    const float e0c = end[0], e1c = end[1], e2c = end[2];

    const float* em = dout + 1 + (size_t)b * TT * 3;
    const int* tg = tags + (size_t)b * TT;

    int tprev = tg[0];
    float a0 = s0 + em[0], a1 = s1 + em[1], a2 = s2 + em[2];
    float num = sel3(tprev, s0, s1, s2) + sel3(tprev, em[0], em[1], em[2]);

    for (int t = 1; t < TT; t++) {
        const float e0 = em[t * 3 + 0], e1 = em[t * 3 + 1], e2 = em[t * 3 + 2];
        const int tt = tg[t];
        const float ee = sel3(tt, e0, e1, e2);
        const float trv = sel3(tprev,
                               sel3(tt, tr[0][0], tr[0][1], tr[0][2]),
                               sel3(tt, tr[1][0], tr[1][1], tr[1][2]),
                               sel3(tt, tr[2][0], tr[2][1], tr[2][2]));
        num += ee + trv;
        tprev = tt;
        const float n0 = lse3(a0 + tr[0][0], a1 + tr[1][0], a2 + tr[2][0]) + e0;
        const float n1 = lse3(a0 + tr[0][1], a1 + tr[1][1], a2 + tr[2][1]) + e1;
        const float n2 = lse3(a0 + tr[0][2], a1 + tr[1][2], a2 + tr[2][2]) + e2;
        a0 = n0; a1 = n1; a2 = n2;
    }
    num += sel3(tprev, e0c, e1c, e2c);
    const float logZ = lse3(a0 + e0c, a1 + e1c, a2 + e2c);
    float val = logZ - num; // per-batch contribution to loss

#pragma unroll
    for (int off = 32; off > 0; off >>= 1) val += __shfl_down(val, off, 64);
    if (b == 0) dout[0] = val / (float)BB;
}

// ---------------- launch ----------------
extern "C" void kernel_launch(void* const* d_in, const int* in_sizes, int n_in,
                              void* d_out, int out_size, void* d_ws, size_t ws_size,
                              hipStream_t stream) {
    const float* x        = (const float*)d_in[0];
    const int*   tags     = (const int*)d_in[1];
    const float* w_ih_l0  = (const float*)d_in[2];
    const float* w_hh_l0  = (const float*)d_in[3];
    const float* b_ih_l0  = (const float*)d_in[4];
    const float* b_hh_l0  = (const float*)d_in[5];
    const float* w_ih_l0r = (const float*)d_in[6];
    const float* w_hh_l0r = (const float*)d_in[7];
    const float* b_ih_l0r = (const float*)d_in[8];
    const float* b_hh_l0r = (const float*)d_in[9];
    const float* w_ih_l1  = (const float*)d_in[10];
    const float* w_hh_l1  = (const float*)d_in[11];
    const float* b_ih_l1  = (const float*)d_in[12];
    const float* b_hh_l1  = (const float*)d_in[13];
    const float* w_ih_l1r = (const float*)d_in[14];
    const float* w_hh_l1r = (const float*)d_in[15];
    const float* b_ih_l1r = (const float*)d_in[16];
    const float* b_hh_l1r = (const float*)d_in[17];
    const float* fc_w     = (const float*)d_in[18];
    const float* fc_b     = (const float*)d_in[19];
    const float* crf_start= (const float*)d_in[20];
    const float* crf_end  = (const float*)d_in[21];
    const float* crf_trans= (const float*)d_in[22];
    float* dout = (float*)d_out;

    uint8_t* ws = (uint8_t*)d_ws;
    // workspace layout (bytes) — same footprint as round 1 (proven to fit)
    unsigned short* xb   = (unsigned short*)(ws + 0);          // 33.5 MB, reused as out1 later
    unsigned short* out1 = xb;
    unsigned short* out0 = (unsigned short*)(ws + 33554432);   // 33.5 MB
    unsigned short* Gf   = (unsigned short*)(ws + 67108864);   // 67 MB
    unsigned short* Gr   = (unsigned short*)(ws + 134217728);  // 67 MB
    unsigned short* wb0  = (unsigned short*)(ws + 201326592);  // 4 x 256 KB
    unsigned short* wb0r = wb0 + 131072;
    unsigned short* wb1  = wb0 + 262144;
    unsigned short* wb1r = wb0 + 393216;

    // 1. convert x and the 4 w_ih matrices to bf16
    cvt4_kernel<<<dim3((16777216 / 4 + 255) / 256), dim3(256), 0, stream>>>(x, xb, 16777216 / 4);
    cvt4_kernel<<<dim3(128), dim3(256), 0, stream>>>(w_ih_l0,  wb0,  131072 / 4);
    cvt4_kernel<<<dim3(128), dim3(256), 0, stream>>>(w_ih_l0r, wb0r, 131072 / 4);
    cvt4_kernel<<<dim3(128), dim3(256), 0, stream>>>(w_ih_l1,  wb1,  131072 / 4);
    cvt4_kernel<<<dim3(128), dim3(256), 0, stream>>>(w_ih_l1r, wb1r, 131072 / 4);

    // 2. layer 0: input projection + MFMA scan
    gemm_ih<<<dim3(1024, 4, 2), dim3(256), 0, stream>>>(
        xb, wb0, wb0r, b_ih_l0, b_hh_l0, b_ih_l0r, b_hh_l0r, Gf, Gr);
    lstm_scan_mfma<<<dim3(32, 2), dim3(512), 0, stream>>>(Gf, Gr, w_hh_l0, w_hh_l0r, out0);

    // 3. layer 1: input projection (reusing G buffers) + MFMA scan
    gemm_ih<<<dim3(1024, 4, 2), dim3(256), 0, stream>>>(
        out0, wb1, wb1r, b_ih_l1, b_hh_l1, b_ih_l1r, b_hh_l1r, Gf, Gr);
    lstm_scan_mfma<<<dim3(32, 2), dim3(512), 0, stream>>>(Gf, Gr, w_hh_l1, w_hh_l1r, out1);

    // 4. emissions
    emis_kernel<<<dim3(256), dim3(256), 0, stream>>>(out1, fc_w, fc_b, dout);

    // 5. CRF NLL -> dout[0]
    crf_kernel<<<dim3(1), dim3(64), 0, stream>>>(tags, crf_start, crf_end, crf_trans, dout);
}